// Round 5
// baseline (81.500 us; speedup 1.0000x reference)
//
#include <hip/hip_runtime.h>

static constexpr int B_ROWS = 1048576;
static constexpr int T_LEN  = 32;
static constexpr int NTHR   = 256;
static constexpr int NBLK   = 2048;                  // partials: 16 KB in d_ws
static constexpr int NCHUNK = B_ROWS / NTHR;         // 4096 chunks of 256 rows

// One HMM step, fully static indexing (rule #20: no runtime-indexed arrays).
// Select-form (cndmask), no divergent per-step branches.
#define HMM_STEP(OF) {                                                        \
    const float of_ = (OF);                                                   \
    const bool ok = alive && (of_ == of_);                                    \
    alive = ok;                                                               \
    const int o = ok ? (int)of_ : 0;                                          \
    const float e0f = (o==0)?fy0:(o==1)?fy1:(o==2)?fy2:(o==3)?fr03:0.0f;      \
    const float e2f = (o==0)?fy4:(o==1)?fy5:(o==2)?fy6:(o==3)?fr23:0.0f;      \
    const float e1f = (o==4)?fy3:0.0f;                                        \
    const double e0 = (double)e0f;                                            \
    const double e2v = (double)e2f;                                           \
    const double e1 = (o==5) ? e15 : (double)e1f;                             \
    const double n0 = (a0*t00 + a1*t10 + a2*t20) * e0;                        \
    const double n1 = (a0*t01 + a1*t11 + a2*t21) * e1;                        \
    const double n2 = (a0*t02 + a1*t12 + a2*t22) * e2v;                       \
    a0 = ok ? n0 : a0;                                                        \
    a1 = ok ? n1 : a1;                                                        \
    a2 = ok ? n2 : a2;                                                        \
}

__global__ __launch_bounds__(NTHR) void hmm_fwd_kernel(
    const float* __restrict__ Y,
    const float* __restrict__ Yo,
    const int*   __restrict__ Pi0,
    double*      __restrict__ partials,
    int nblk)
{
    // Reference quirk: E[b,1,5] = 1 - Ysa[1,3] for ALL b (batch row 1, col 3).
    const double e15 = 1.0 - (double)Y[1 * 13 + 3];   // uniform -> s_load
    const double pi0 = (double)Pi0[0];
    const double pi1 = (double)Pi0[1];
    const double pi2 = (double)Pi0[2];

    // Y panel staged per 256-row chunk: flat copy keeps [row][13] layout.
    // Read stride 13 (odd, coprime with 32) -> bank-conflict-free.
    __shared__ float sY[NTHR * 13];

    double local = 0.0;
    for (int chunk = blockIdx.x; chunk < NCHUNK; chunk += nblk) {
        const int rowBase = chunk * NTHR;
        const float* gY = Y + (size_t)rowBase * 13;
        __syncthreads();   // protect sY from previous iteration's readers
        #pragma unroll
        for (int k = 0; k < 13; ++k)
            sY[k * NTHR + threadIdx.x] = gY[k * NTHR + threadIdx.x];  // coalesced
        __syncthreads();

        const int r = rowBase + threadIdx.x;   // always < B_ROWS (4096*256 = 1M)
        const float* y = &sY[threadIdx.x * 13];
        const float fy0 = y[0], fy1 = y[1], fy2 = y[2], fy3 = y[3];
        const float fy4 = y[4], fy5 = y[5], fy6 = y[6];
        const float fr03 = 1.0f - fy0 - fy1 - fy2;
        const float fr23 = 1.0f - fy4 - fy5 - fy6;
        const double t00 = (double)y[7],  t01 = (double)y[8];
        const double t10 = (double)y[9],  t11 = (double)y[10];
        const double t20 = (double)y[11], t21 = (double)y[12];
        const double t02 = 1.0 - t00 - t01;
        const double t12 = 1.0 - t10 - t11;
        const double t22 = 1.0 - t20 - t21;

        const float4* yo4 = reinterpret_cast<const float4*>(Yo + (size_t)r * T_LEN);
        // First half of the obs row (t = 0..15): 64 B, always needed (len >= 4).
        const float4 v0 = yo4[0], v1 = yo4[1], v2 = yo4[2], v3 = yo4[3];

        // t = 0 init (always valid)
        double a0, a1, a2;
        {
            const int o = (int)v0.x;
            const float e0f = (o==0)?fy0:(o==1)?fy1:(o==2)?fy2:(o==3)?fr03:0.0f;
            const float e2f = (o==0)?fy4:(o==1)?fy5:(o==2)?fy6:(o==3)?fr23:0.0f;
            const double e1 = (o==4)?(double)fy3:(o==5)?e15:0.0;
            a0 = pi0 * (double)e0f;
            a1 = pi1 * e1;
            a2 = pi2 * (double)e2f;
        }
        bool alive = true;

        HMM_STEP(v0.y) HMM_STEP(v0.z) HMM_STEP(v0.w)
        HMM_STEP(v1.x) HMM_STEP(v1.y) HMM_STEP(v1.z) HMM_STEP(v1.w)
        HMM_STEP(v2.x) HMM_STEP(v2.y) HMM_STEP(v2.z) HMM_STEP(v2.w)
        HMM_STEP(v3.x) HMM_STEP(v3.y) HMM_STEP(v3.z) HMM_STEP(v3.w)

        // Second half (t = 16..31): fetch only if this lane's row is still live.
        if (alive) {
            const float4 v4 = yo4[4], v5 = yo4[5], v6 = yo4[6], v7 = yo4[7];
            HMM_STEP(v4.x) HMM_STEP(v4.y) HMM_STEP(v4.z) HMM_STEP(v4.w)
            HMM_STEP(v5.x) HMM_STEP(v5.y) HMM_STEP(v5.z) HMM_STEP(v5.w)
            HMM_STEP(v6.x) HMM_STEP(v6.y) HMM_STEP(v6.z) HMM_STEP(v6.w)
            HMM_STEP(v7.x) HMM_STEP(v7.y) HMM_STEP(v7.z) HMM_STEP(v7.w)
        }

        double asum = a0 + a1 + a2;
        // Guard: exact-0/NaN alpha-sum would emit -inf/NaN and poison the sum.
        if (!(asum >= 1e-300)) asum = 1e-300;
        local += log(asum);
    }

    // Block reduction (double): wave shuffle-reduce, then LDS across 4 waves.
    #pragma unroll
    for (int off = 32; off > 0; off >>= 1)
        local += __shfl_down(local, off, 64);
    __shared__ double sred[NTHR / 64];
    const int lane = threadIdx.x & 63;
    const int wv   = threadIdx.x >> 6;
    if (lane == 0) sred[wv] = local;
    __syncthreads();
    if (threadIdx.x == 0) {
        double s = 0.0;
        #pragma unroll
        for (int i = 0; i < NTHR / 64; ++i) s += sred[i];
        partials[blockIdx.x] = s;
    }
}

__global__ __launch_bounds__(256) void hmm_final_kernel(
    const double* __restrict__ partials, float* __restrict__ out, int nblk)
{
    double local = 0.0;
    for (int i = threadIdx.x; i < nblk; i += 256) local += partials[i];
    #pragma unroll
    for (int off = 32; off > 0; off >>= 1)
        local += __shfl_down(local, off, 64);
    __shared__ double sred[4];
    const int lane = threadIdx.x & 63;
    const int wv   = threadIdx.x >> 6;
    if (lane == 0) sred[wv] = local;
    __syncthreads();
    if (threadIdx.x == 0) {
        double s = sred[0] + sred[1] + sred[2] + sred[3];
        out[0] = (float)(-s / (double)B_ROWS);
    }
}

extern "C" void kernel_launch(void* const* d_in, const int* in_sizes, int n_in,
                              void* d_out, int out_size, void* d_ws, size_t ws_size,
                              hipStream_t stream)
{
    // Identify inputs by size rather than trusting order.
    const float* Y   = nullptr;   // (B, 13) f32
    const float* Yo  = nullptr;   // (B, 32) f32 (NaN-masked obs)
    const int*   Pi0 = nullptr;   // (3,) i32
    for (int i = 0; i < n_in; ++i) {
        if (in_sizes[i] == B_ROWS * 13)      Y   = (const float*)d_in[i];
        else if (in_sizes[i] == B_ROWS * 32) Yo  = (const float*)d_in[i];
        else if (in_sizes[i] == 3)           Pi0 = (const int*)d_in[i];
    }

    int nblk = NBLK;
    if (ws_size < (size_t)NBLK * sizeof(double)) {
        nblk = (int)(ws_size / sizeof(double));
        if (nblk < 1) nblk = 1;
    }
    double* partials = (double*)d_ws;

    hmm_fwd_kernel<<<nblk, NTHR, 0, stream>>>(Y, Yo, Pi0, partials, nblk);
    hmm_final_kernel<<<1, 256, 0, stream>>>(partials, (float*)d_out, nblk);
}

// Round 6
// 77.288 us; speedup vs baseline: 1.0545x; 1.0545x over previous
//
#include <hip/hip_runtime.h>

static constexpr int B_ROWS = 1048576;
static constexpr int T_LEN  = 32;
static constexpr int NTHR   = 256;
static constexpr int NCHUNK = B_ROWS / NTHR;         // 4096 chunks of 256 rows
static constexpr int NBLK_MAX = 4096;                // partials: 32 KB in d_ws

// One HMM step in f32, fully static indexing, select-form (no branches).
#define HMM_STEP(OF) {                                                        \
    const float of_ = (OF);                                                   \
    const bool ok = alive && (of_ == of_);                                    \
    alive = ok;                                                               \
    const int o = ok ? (int)of_ : 0;                                          \
    const float e0f = (o==0)?fy0:(o==1)?fy1:(o==2)?fy2:(o==3)?fr03:0.0f;      \
    const float e2f = (o==0)?fy4:(o==1)?fy5:(o==2)?fy6:(o==3)?fr23:0.0f;      \
    const float e1f = (o==4)?fy3:(o==5)?fe15:0.0f;                            \
    const float n0 = (a0*t00 + a1*t10 + a2*t20) * e0f;                        \
    const float n1 = (a0*t01 + a1*t11 + a2*t21) * e1f;                        \
    const float n2 = (a0*t02 + a1*t12 + a2*t22) * e2f;                        \
    a0 = ok ? n0 : a0;                                                        \
    a1 = ok ? n1 : a1;                                                        \
    a2 = ok ? n2 : a2;                                                        \
}

// Power-of-2 rescale: keeps alpha in f32 normal range. No 'alive' gating
// needed: a spurious rescale is exactly compensated by kk and self-limits
// (post-rescale s >= 1e-2 -> no further fires). Worst 2-step decay from
// 1e-2 with emissions ~1e-10 each: 1e-22, still normal f32.
#define RESCALE {                                                             \
    const float s_ = a0 + a1 + a2;                                            \
    const bool sc = (s_ < 1e-2f);                                             \
    const float m_ = sc ? 0x1p20f : 1.0f;                                     \
    a0 *= m_; a1 *= m_; a2 *= m_;                                             \
    kk += sc ? 1 : 0;                                                         \
}

#define STEP2(A, B) HMM_STEP(A) HMM_STEP(B) RESCALE

__global__ __launch_bounds__(NTHR) void hmm_fwd_kernel(
    const float* __restrict__ Y,
    const float* __restrict__ Yo,
    const int*   __restrict__ Pi0,
    double*      __restrict__ partials,
    int nblk)
{
    // Reference quirk: E[b,1,5] = 1 - Ysa[1,3] for ALL b (batch row 1, col 3).
    const float fe15 = 1.0f - Y[1 * 13 + 3];   // uniform -> scalar load
    const float pi0 = (float)Pi0[0];
    const float pi1 = (float)Pi0[1];
    const float pi2 = (float)Pi0[2];

    double local = 0.0;
    for (int chunk = blockIdx.x; chunk < NCHUNK; chunk += nblk) {
        const int r = chunk * NTHR + threadIdx.x;

        // Obs row: 32 floats, 128B-aligned. Load ALL of it up front ----
        // no alive-dependent second load, so no mid-row latency exposure.
        const float4* yo4 = reinterpret_cast<const float4*>(Yo + (size_t)r * T_LEN);
        const float4 v0 = yo4[0], v1 = yo4[1], v2 = yo4[2], v3 = yo4[3];
        const float4 v4 = yo4[4], v5 = yo4[5], v6 = yo4[6], v7 = yo4[7];

        const float* y = Y + (size_t)r * 13;
        const float fy0 = y[0], fy1 = y[1], fy2 = y[2], fy3 = y[3];
        const float fy4 = y[4], fy5 = y[5], fy6 = y[6];
        const float fr03 = 1.0f - fy0 - fy1 - fy2;
        const float fr23 = 1.0f - fy4 - fy5 - fy6;
        const float t00 = y[7],  t01 = y[8];
        const float t10 = y[9],  t11 = y[10];
        const float t20 = y[11], t21 = y[12];
        const float t02 = 1.0f - t00 - t01;
        const float t12 = 1.0f - t10 - t11;
        const float t22 = 1.0f - t20 - t21;

        // t = 0 init (always valid: length >= 4)
        float a0, a1, a2;
        {
            const int o = (int)v0.x;
            const float e0f = (o==0)?fy0:(o==1)?fy1:(o==2)?fy2:(o==3)?fr03:0.0f;
            const float e2f = (o==0)?fy4:(o==1)?fy5:(o==2)?fy6:(o==3)?fr23:0.0f;
            const float e1f = (o==4)?fy3:(o==5)?fe15:0.0f;
            a0 = pi0 * e0f;
            a1 = pi1 * e1f;
            a2 = pi2 * e2f;
        }
        bool alive = true;
        int  kk = 0;

        HMM_STEP(v0.y)            // t=1
        STEP2(v0.z, v0.w)         // t=2,3
        STEP2(v1.x, v1.y)         // 4,5
        STEP2(v1.z, v1.w)         // 6,7
        STEP2(v2.x, v2.y)         // 8,9
        STEP2(v2.z, v2.w)         // 10,11
        STEP2(v3.x, v3.y)         // 12,13
        STEP2(v3.z, v3.w)         // 14,15
        STEP2(v4.x, v4.y)         // 16,17
        STEP2(v4.z, v4.w)         // 18,19
        STEP2(v5.x, v5.y)         // 20,21
        STEP2(v5.z, v5.w)         // 22,23
        STEP2(v6.x, v6.y)         // 24,25
        STEP2(v6.z, v6.w)         // 26,27
        STEP2(v7.x, v7.y)         // 28,29
        STEP2(v7.z, v7.w)         // 30,31

        float asum = a0 + a1 + a2;
        // Guard: exact-0/NaN alpha-sum -> clamp so output stays finite.
        if (!(asum >= 1e-35f)) asum = 1e-35f;
        local += (double)logf(asum)
               - (double)kk * (20.0 * 0.6931471805599453);
    }

    // Block reduction (double): wave shuffle-reduce, then LDS across 4 waves.
    #pragma unroll
    for (int off = 32; off > 0; off >>= 1)
        local += __shfl_down(local, off, 64);
    __shared__ double sred[NTHR / 64];
    const int lane = threadIdx.x & 63;
    const int wv   = threadIdx.x >> 6;
    if (lane == 0) sred[wv] = local;
    __syncthreads();
    if (threadIdx.x == 0) {
        double s = 0.0;
        #pragma unroll
        for (int i = 0; i < NTHR / 64; ++i) s += sred[i];
        partials[blockIdx.x] = s;
    }
}

__global__ __launch_bounds__(256) void hmm_final_kernel(
    const double* __restrict__ partials, float* __restrict__ out, int nblk)
{
    double local = 0.0;
    for (int i = threadIdx.x; i < nblk; i += 256) local += partials[i];
    #pragma unroll
    for (int off = 32; off > 0; off >>= 1)
        local += __shfl_down(local, off, 64);
    __shared__ double sred[4];
    const int lane = threadIdx.x & 63;
    const int wv   = threadIdx.x >> 6;
    if (lane == 0) sred[wv] = local;
    __syncthreads();
    if (threadIdx.x == 0) {
        double s = sred[0] + sred[1] + sred[2] + sred[3];
        out[0] = (float)(-s / (double)B_ROWS);
    }
}

extern "C" void kernel_launch(void* const* d_in, const int* in_sizes, int n_in,
                              void* d_out, int out_size, void* d_ws, size_t ws_size,
                              hipStream_t stream)
{
    // Identify inputs by size rather than trusting order.
    const float* Y   = nullptr;   // (B, 13) f32
    const float* Yo  = nullptr;   // (B, 32) f32 (NaN-masked obs)
    const int*   Pi0 = nullptr;   // (3,) i32
    for (int i = 0; i < n_in; ++i) {
        if (in_sizes[i] == B_ROWS * 13)      Y   = (const float*)d_in[i];
        else if (in_sizes[i] == B_ROWS * 32) Yo  = (const float*)d_in[i];
        else if (in_sizes[i] == 3)           Pi0 = (const int*)d_in[i];
    }

    int nblk = NBLK_MAX;                              // 4096 -> 1 row/thread
    if (ws_size < (size_t)NBLK_MAX * sizeof(double)) {
        nblk = (int)(ws_size / sizeof(double));
        if (nblk < 1) nblk = 1;
    }
    double* partials = (double*)d_ws;

    hmm_fwd_kernel<<<nblk, NTHR, 0, stream>>>(Y, Yo, Pi0, partials, nblk);
    hmm_final_kernel<<<1, 256, 0, stream>>>(partials, (float*)d_out, nblk);
}